// Round 9
// baseline (226.912 us; speedup 1.0000x reference)
//
#include <hip/hip_runtime.h>
#include <hip/hip_cooperative_groups.h>
#include <math.h>

namespace cg = cooperative_groups;

typedef _Float16 f16x8 __attribute__((ext_vector_type(8)));
typedef float f32x4 __attribute__((ext_vector_type(4)));

// ---------------------------------------------------------------------------
// Single cooperative kernel, 256 blocks x 512 thr (1 block/CU, 137KB LDS).
//   P0: prefetch qry 64px tile -> qtf (rides under P1's HBM stream)
//   P1: pool sup_x (5 planes/block) -> cand_T[c][m] coalesced; sup_y -> yv_ws
//   P2: blocks 0..39 finalize 32 protos each -> pro_h f16, chunk g ^ (m&7)
//   P3: masks (per-block, LDS), qnorm -> qs f16 (g ^ (px&7)), B-frags to regs,
//       10x128m pipeline: per-wave LDS dbuf, global_load_lds, counted vmcnt.
// pred[px] = sum_m softmax(mask? d : NEG)_m * d_m, d = 20*<qry_n,pro_n> <= 20
// -> fixed-max softmax: e = mk*exp(d-20) in [e^-40,1]; masked -> exactly 0.
// ---------------------------------------------------------------------------

__device__ __forceinline__ void gload_lds16h(const _Float16* g, _Float16* l) {
    __builtin_amdgcn_global_load_lds((const __attribute__((address_space(1))) unsigned int*)g,
                                     (__attribute__((address_space(3))) unsigned int*)l,
                                     16, 0, 0);
}
__device__ __forceinline__ void gload_lds16f(const float* g, float* l) {
    __builtin_amdgcn_global_load_lds((const __attribute__((address_space(1))) unsigned int*)g,
                                     (__attribute__((address_space(3))) unsigned int*)l,
                                     16, 0, 0);
}

__device__ __forceinline__ void stage_tile(const _Float16* __restrict__ pro_h,
                                           int tile, _Float16* dst, int w, int l) {
#pragma unroll
    for (int i = 0; i < 8; ++i) {
        const int off = w * 4096 + i * 512 + l * 8;
        gload_lds16h(pro_h + (size_t)tile * 32768 + off, dst + off);
    }
}

__device__ __forceinline__ void compute_tile(const _Float16* __restrict__ pb,
                                             const float* __restrict__ msp,
                                             const f16x8 (&bfr)[4][8],
                                             int row, int ln7, int lq,
                                             float (&Sa)[4], float (&Wa)[4]) {
    f32x4 acc[4];
#pragma unroll
    for (int p = 0; p < 4; ++p) acc[p] = (f32x4){0.f, 0.f, 0.f, 0.f};
#pragma unroll
    for (int ks = 0; ks < 8; ++ks) {
        const int ch = (ks * 4 + lq) ^ ln7;
        const f16x8 a = *(const f16x8*)(pb + row * 256 + ch * 8);
#pragma unroll
        for (int p = 0; p < 4; ++p)
            acc[p] = __builtin_amdgcn_mfma_f32_16x16x32_f16(a, bfr[p][ks], acc[p], 0, 0, 0);
    }
    const f32x4 mkv = *(const f32x4*)(msp + lq * 4);
#pragma unroll
    for (int p = 0; p < 4; ++p) {
        float ssum = 0.f, wsum = 0.f;
#pragma unroll
        for (int r = 0; r < 4; ++r) {
            const float d = 20.f * acc[p][r];
            const float e = mkv[r] * __expf(d - 20.f);
            ssum += e; wsum += e * d;
        }
        Sa[p] += ssum; Wa[p] += wsum;
    }
}

__global__ __launch_bounds__(512, 2) void fused_kernel(const float* __restrict__ qry,
                                                       const float* __restrict__ sup_x,
                                                       const float* __restrict__ sup_y,
                                                       float* __restrict__ cand_T,
                                                       float* __restrict__ yv_ws,
                                                       _Float16* __restrict__ pro_h,
                                                       float* __restrict__ out) {
    __shared__ __align__(16) _Float16 arena[65536];   // 128 KB
    __shared__ float scr[1024];
    __shared__ float2 stats[64];
    __shared__ float ms[1280];
    __shared__ int iflags[2];

    float*     qtf  = (float*)arena;            // [0,64K)  P0/P3 qry staging
    float*     hs   = (float*)(arena + 32768);  // [64K,80K) P1 pool scratch
    float*     p2t  = (float*)(arena + 32768);  // [64K,97K) P2 tile (b<40)
    _Float16*  qs   = arena + 32768;            // [64K,96K) P3 qry f16
    _Float16*  buf0 = arena;                    // [0,64K)  P3 proto dbuf
    _Float16*  buf1 = arena + 32768;            // [64K,128K)
    float*     red  = (float*)arena;            // [0,16K)  epilogue

    const int b = blockIdx.x, t = threadIdx.x;
    const int w = t >> 6, l = t & 63;
    const int ln = l & 15, lq = l >> 4, ln7 = ln & 7;
    const int px0 = b * 64;
    cg::grid_group grid = cg::this_grid();

    // ---- P0: prefetch qry tile into qtf ----
#pragma unroll
    for (int i = 0; i < 8; ++i) {
        const int c = i * 32 + (t >> 4);
        gload_lds16f(qry + (size_t)c * 16384 + px0 + (t & 15) * 4,
                     qtf + i * 2048 + t * 4);
    }

    // ---- P1: pool 5 sup_x planes/block ----
#pragma unroll 1
    for (int p = 0; p < 5; ++p) {
        const int plane = b * 5 + p;
        const int s = plane >> 8, c = plane & 255;
        const float4* pl = (const float4*)(sup_x + (size_t)plane * 16384);
        float4 v[8];
#pragma unroll
        for (int i = 0; i < 8; ++i) v[i] = pl[i * 512 + t];
        __syncthreads();                       // prev reduce done -> hs free
#pragma unroll
        for (int i = 0; i < 8; ++i)
            hs[i * 512 + t] = v[i].x + v[i].y + v[i].z + v[i].w;
        __syncthreads();
        if (t < 256) {
            const int gy = t >> 4, gx = t & 15;
            float sum = 0.f;
#pragma unroll
            for (int rr = 0; rr < 8; ++rr)
                sum += hs[(gy * 8 + rr) * 32 + 2 * gx] + hs[(gy * 8 + rr) * 32 + 2 * gx + 1];
            cand_T[(size_t)c * 1280 + s * 256 + t] = sum * (1.f / 64.f);
        }
    }
    if (b < 5 && t < 256) {                    // pool sup_y shot b
        const int gy = t >> 4, gx = t & 15;
        const float* base = sup_y + b * 16384 + gy * 1024 + gx * 8;
        float sum = 0.f;
#pragma unroll
        for (int rr = 0; rr < 8; ++rr) {
            const float4 a = *(const float4*)(base + rr * 128);
            const float4 bb = *(const float4*)(base + rr * 128 + 4);
            sum += a.x + a.y + a.z + a.w + bb.x + bb.y + bb.z + bb.w;
        }
        yv_ws[b * 256 + t] = sum * (1.f / 64.f);
    }
    __threadfence();
    grid.sync();

    // ---- P2: blocks 0..39 finalize 32 protos each ----
    if (b < 40) {
        const int m0 = b * 32;
#pragma unroll
        for (int it = 0; it < 16; ++it) {      // [256c][32m] tile, 128B runs
            const int idx = it * 512 + t;
            const int c = idx >> 5, mm = idx & 31;
            p2t[c * 33 + mm] = cand_T[(size_t)c * 1280 + m0 + mm];
        }
        __syncthreads();
        {
            const int ml = t & 31, part = t >> 5;   // 16 parts x 16 c
            float s1 = 0.f, s2 = 0.f;
#pragma unroll
            for (int cc = 0; cc < 16; ++cc) {
                const float x = p2t[(part * 16 + cc) * 33 + ml];
                s1 += x; s2 += x * x;
            }
            scr[part * 32 + ml] = s1; scr[512 + part * 32 + ml] = s2;
        }
        __syncthreads();
        if (t < 32) {
            float S1 = 0.f, S2 = 0.f;
#pragma unroll
            for (int p = 0; p < 16; ++p) { S1 += scr[p * 32 + t]; S2 += scr[512 + p * 32 + t]; }
            const float mu = S1 * (1.f / 256.f);
            const float nrm = sqrtf(fmaxf(S2 - 256.f * mu * mu, 0.f));
            scr[t] = mu; scr[32 + t] = 1.f / fmaxf(nrm, 1e-4f);
        }
        __syncthreads();
        {
            const int mloc = t >> 4, q = t & 15;
            const float mu = scr[mloc], inv = scr[32 + mloc];
#pragma unroll
            for (int u = 0; u < 2; ++u) {
                const int g = u * 16 + q;
                f16x8 hv;
#pragma unroll
                for (int j = 0; j < 8; ++j)
                    hv[j] = (_Float16)((p2t[(g * 8 + j) * 33 + mloc] - mu) * inv);
                *(f16x8*)(pro_h + (size_t)(m0 + mloc) * 256 + ((g ^ (mloc & 7)) << 3)) = hv;
            }
        }
    }
    __threadfence();
    grid.sync();
    __threadfence();

    // ---- P3a: masks (per-block, no global round-trip) ----
    if (t < 2) iflags[t] = 0;
    __syncthreads();
    float yv3[3];
#pragma unroll
    for (int it = 0; it < 3; ++it) {
        const int idx = it * 512 + t;
        yv3[it] = (idx < 1280) ? yv_ws[idx] : 0.f;
    }
    {
        int f0 = 0, f1 = 0;
#pragma unroll
        for (int it = 0; it < 3; ++it) { if (yv3[it] > 0.5f) f0 = 1; if (yv3[it] > 0.1f) f1 = 1; }
        if (f0) atomicOr(&iflags[0], 1);
        if (f1) atomicOr(&iflags[1], 1);
    }
    __syncthreads();
    {
        const int mode = iflags[0] ? 0 : (iflags[1] ? 1 : 2);
#pragma unroll
        for (int it = 0; it < 3; ++it) {
            const int idx = it * 512 + t;
            if (idx < 1280)
                ms[idx] = (mode == 0) ? (yv3[it] > 0.5f ? 1.f : 0.f)
                        : (mode == 1) ? (yv3[it] > 0.1f ? 1.f : 0.f) : 1.f;
        }
    }

    // ---- P3b: qnorm from prefetched qtf ----
    {
        const int p = t & 63, q8 = t >> 6;
        float s1 = 0.f, s2 = 0.f;
        for (int cc = 0; cc < 32; ++cc) {
            const float x = qtf[(q8 * 32 + cc) * 64 + p];
            s1 += x; s2 += x * x;
        }
        scr[q8 * 64 + p] = s1; scr[512 + q8 * 64 + p] = s2;
    }
    __syncthreads();
    if (t < 64) {
        float S1 = 0.f, S2 = 0.f;
        for (int q = 0; q < 8; ++q) { S1 += scr[q * 64 + t]; S2 += scr[512 + q * 64 + t]; }
        const float mu = S1 * (1.f / 256.f);
        const float nrm = sqrtf(fmaxf(S2 - 256.f * mu * mu, 0.f));
        stats[t] = make_float2(mu, 1.f / fmaxf(nrm, 1e-4f));
    }
    __syncthreads();
    {
        const int px = t & 63, e = t >> 6;
        const float2 st = stats[px];
#pragma unroll
        for (int u = 0; u < 4; ++u) {
            const int g = e * 4 + u;
            f16x8 hv;
#pragma unroll
            for (int j = 0; j < 8; ++j)
                hv[j] = (_Float16)((qtf[(g * 8 + j) * 64 + px] - st.x) * st.y);
            *(f16x8*)(qs + px * 256 + ((g ^ (px & 7)) << 3)) = hv;
        }
    }
    __syncthreads();

    // ---- P3c: hoist B fragments, then per-wave counted-vmcnt pipeline ----
    f16x8 bfr[4][8];
#pragma unroll
    for (int p = 0; p < 4; ++p) {
        const int px = p * 16 + ln;
        const int sB = px & 7;
#pragma unroll
        for (int ks = 0; ks < 8; ++ks) {
            const int g = ks * 4 + lq;
            bfr[p][ks] = *(const f16x8*)(qs + px * 256 + ((g ^ sB) << 3));
        }
    }
    __syncthreads();   // all waves done with qs/qtf -> arena free for buffers

    stage_tile(pro_h, 0, buf0, w, l);
    stage_tile(pro_h, 1, buf1, w, l);

    const int row = w * 16 + ln;
    float Sa[4] = {0.f, 0.f, 0.f, 0.f}, Wa[4] = {0.f, 0.f, 0.f, 0.f};

#pragma unroll 1
    for (int tile = 0; tile < 10; ++tile) {
        if (tile < 8) asm volatile("s_waitcnt vmcnt(8)" ::: "memory");
        else          asm volatile("s_waitcnt vmcnt(0)" ::: "memory");
        compute_tile((tile & 1) ? buf1 : buf0, ms + tile * 128 + w * 16,
                     bfr, row, ln7, lq, Sa, Wa);
        if (tile < 8) {
            asm volatile("s_waitcnt lgkmcnt(0)" ::: "memory");
            __builtin_amdgcn_sched_barrier(0);
            stage_tile(pro_h, tile + 2, (tile & 1) ? buf1 : buf0, w, l);
        }
    }

    __syncthreads();   // all waves done with buffers -> red overlay safe
#pragma unroll
    for (int p = 0; p < 4; ++p) {
        const int px = p * 16 + ln;
        const int slot = (w * 4 + lq + px) & 31;
        red[px * 32 + slot] = Sa[p];
        red[2048 + px * 32 + slot] = Wa[p];
    }
    __syncthreads();
    if (t < 64) {
        float S = 0.f, W = 0.f;
        for (int s = 0; s < 32; ++s) {
            const int slot = (s + t) & 31;
            S += red[t * 32 + slot];
            W += red[2048 + t * 32 + slot];
        }
        out[px0 + t] = W / S;
    }
}

extern "C" void kernel_launch(void* const* d_in, const int* in_sizes, int n_in,
                              void* d_out, int out_size, void* d_ws, size_t ws_size,
                              hipStream_t stream) {
    const float* qry   = (const float*)d_in[0];   // 256*16384
    const float* sup_x = (const float*)d_in[1];   // 5*256*16384
    const float* sup_y = (const float*)d_in[2];   // 5*16384
    float* out = (float*)d_out;                   // 16384

    char* ws = (char*)d_ws;
    float*     cand_T = (float*)ws;               ws += 256 * 1280 * 4;    // 1.25 MB
    float*     yv_ws  = (float*)ws;               ws += 1280 * 4;
    _Float16*  pro_h  = (_Float16*)ws;            /* 640 KB */

    void* args[7] = {(void*)&qry, (void*)&sup_x, (void*)&sup_y,
                     (void*)&cand_T, (void*)&yv_ws, (void*)&pro_h, (void*)&out};
    hipLaunchCooperativeKernel((const void*)fused_kernel, dim3(256), dim3(512),
                               args, 0, stream);
}

// Round 10
// 40.750 us; speedup vs baseline: 5.5683x; 5.5683x over previous
//
#include <hip/hip_runtime.h>
#include <math.h>

typedef _Float16 f16x8 __attribute__((ext_vector_type(8)));
typedef float f32x4 __attribute__((ext_vector_type(4)));

// ---------------------------------------------------------------------------
// Geometry: qry (256c, 16384px) f32; sup_x (5,256,16384) f32; sup_y (5,16384)
// protos M=1280, C=256, PX=16384. out (16384) f32.
// pred[px] = sum_m softmax(mask? d : NEG)_m * d_m, d = 20*<qry_n[px],pro_n[m]>
// d <= 20 -> FIXED-max softmax: e = mk*exp(d-20) in [e^-40, 1]. Masked -> 0.
// pro_h PRE-SWIZZLED in global: row m, 16B chunk g stored at g ^ (m&7)
// (byte bits 4-6 -> bank bits 2-4: conflict-free b128 reads). Main stages
// tiles LINEARLY via global_load_lds, per-wave 2-deep dbuf, counted vmcnt.
// NOTE (R9 lesson): cooperative grid.sync() costs ~90us on MI355X - never
// worth it to save ~2us launch gaps. 3 separate kernels is the right shape.
// ---------------------------------------------------------------------------

// K1: blocks 0..1279 pool plane (s,c) of sup_x -> cand_T[c][s*256+g] (coalesced
//     1KB/block write). Blocks 1280..1284 pool sup_y shot r -> yv_ws.
__global__ __launch_bounds__(256) void pool_kernel(const float* __restrict__ sup_x,
                                                   const float* __restrict__ sup_y,
                                                   float* __restrict__ cand_T,
                                                   float* __restrict__ yv_ws) {
    const int b = blockIdx.x, t = threadIdx.x;
    if (b < 1280) {
        __shared__ float hs[4096];          // [row 128][col4 32] horizontal 4-sums
        const int s = b >> 8, c = b & 255;
        const float4* plane = (const float4*)(sup_x + (size_t)(s * 256 + c) * 16384);
#pragma unroll
        for (int it = 0; it < 16; ++it) {   // contiguous 4KB per issue
            const float4 v = plane[it * 256 + t];
            hs[it * 256 + t] = v.x + v.y + v.z + v.w;
        }
        __syncthreads();
        const int gy = t >> 4, gx = t & 15;
        float sum = 0.f;
#pragma unroll
        for (int rr = 0; rr < 8; ++rr)
            sum += hs[(gy * 8 + rr) * 32 + 2 * gx] + hs[(gy * 8 + rr) * 32 + 2 * gx + 1];
        cand_T[(size_t)c * 1280 + s * 256 + t] = sum * (1.f / 64.f);
    } else {
        const int r = b - 1280;
        const int gy = t >> 4, gx = t & 15;
        const float* base = sup_y + r * 16384 + gy * 1024 + gx * 8;
        float sum = 0.f;
#pragma unroll
        for (int rr = 0; rr < 8; ++rr) {
            const float4 a = *(const float4*)(base + rr * 128);
            const float4 bb = *(const float4*)(base + rr * 128 + 4);
            sum += a.x + a.y + a.z + a.w + bb.x + bb.y + bb.z + bb.w;
        }
        yv_ws[r * 256 + t] = sum * (1.f / 64.f);
    }
}

// K2: blocks 0..79 finalize 16 protos each -> pro_h f16 (global-swizzled);
//     block 80: mask mode + maskf. Wide grid: ~1.5us instead of 4us.
__global__ __launch_bounds__(256) void fin_kernel(const float* __restrict__ cand_T,
                                                  const float* __restrict__ yv_ws,
                                                  _Float16* __restrict__ pro_h,
                                                  float* __restrict__ maskf) {
    const int b = blockIdx.x, t = threadIdx.x;
    if (b < 80) {
        __shared__ float tile[256 * 17];    // [c][17] padded
        __shared__ float scr[544];
        const int m0 = b * 16;
#pragma unroll
        for (int it = 0; it < 16; ++it) {   // 64B runs, 16 c-rows per issue
            const int idx = it * 256 + t;
            const int c = idx >> 4, mm = idx & 15;
            tile[c * 17 + mm] = cand_T[(size_t)c * 1280 + m0 + mm];
        }
        __syncthreads();
        {   // stats: 16 m x 16 c-parts
            const int mm = t & 15, part = t >> 4;
            float s1 = 0.f, s2 = 0.f;
#pragma unroll
            for (int cc = 0; cc < 16; ++cc) {
                const float x = tile[(part * 16 + cc) * 17 + mm];
                s1 += x; s2 += x * x;
            }
            scr[part * 16 + mm] = s1; scr[256 + part * 16 + mm] = s2;
        }
        __syncthreads();
        if (t < 16) {
            float S1 = 0.f, S2 = 0.f;
#pragma unroll
            for (int p = 0; p < 16; ++p) { S1 += scr[p * 16 + t]; S2 += scr[256 + p * 16 + t]; }
            const float mu = S1 * (1.f / 256.f);
            const float nrm = sqrtf(fmaxf(S2 - 256.f * mu * mu, 0.f));
            scr[512 + t] = mu; scr[528 + t] = 1.f / fmaxf(nrm, 1e-4f);
        }
        __syncthreads();
        {   // write 16 m x 256 ch f16, swizzled chunk g ^ (m&7)
            const int mloc = t >> 4, q = t & 15;
            const float mu = scr[512 + mloc], inv = scr[528 + mloc];
#pragma unroll
            for (int u = 0; u < 2; ++u) {
                const int g = u * 16 + q;
                f16x8 hv;
#pragma unroll
                for (int j = 0; j < 8; ++j)
                    hv[j] = (_Float16)((tile[(g * 8 + j) * 17 + mloc] - mu) * inv);
                *(f16x8*)(pro_h + (size_t)(m0 + mloc) * 256 + ((g ^ (mloc & 7)) << 3)) = hv;
            }
        }
    } else {
        __shared__ int flags[2];
        if (t < 2) flags[t] = 0;
        __syncthreads();
        float yloc[5];
#pragma unroll
        for (int it = 0; it < 5; ++it) {
            const float y = yv_ws[it * 256 + t];
            yloc[it] = y;
            if (y > 0.5f) atomicOr(&flags[0], 1);
            if (y > 0.1f) atomicOr(&flags[1], 1);
        }
        __syncthreads();
        const int mode = flags[0] ? 0 : (flags[1] ? 1 : 2);
#pragma unroll
        for (int it = 0; it < 5; ++it) {
            const float y = yloc[it];
            maskf[it * 256 + t] = (mode == 0) ? (y > 0.5f ? 1.f : 0.f)
                                : (mode == 1) ? (y > 0.1f ? 1.f : 0.f) : 1.f;
        }
    }
}

__device__ __forceinline__ void gload_lds16h(const _Float16* g, _Float16* l) {
    __builtin_amdgcn_global_load_lds((const __attribute__((address_space(1))) unsigned int*)g,
                                     (__attribute__((address_space(3))) unsigned int*)l,
                                     16, 0, 0);
}
__device__ __forceinline__ void gload_lds16f(const float* g, float* l) {
    __builtin_amdgcn_global_load_lds((const __attribute__((address_space(1))) unsigned int*)g,
                                     (__attribute__((address_space(3))) unsigned int*)l,
                                     16, 0, 0);
}

// stage one 128m x 256c f16 tile: wave w stages ITS OWN 16 rows (8KB slice)
__device__ __forceinline__ void stage_tile(const _Float16* __restrict__ pro_h,
                                           int tile, _Float16* dst, int w, int l) {
#pragma unroll
    for (int i = 0; i < 8; ++i) {
        const int off = w * 4096 + i * 512 + l * 8;
        gload_lds16h(pro_h + (size_t)tile * 32768 + off, dst + off);
    }
}

// compute one 128-m tile: wave owns rows w*16..w*16+15 (its own slice).
__device__ __forceinline__ void compute_tile(const _Float16* __restrict__ pb,
                                             const float* __restrict__ msp,
                                             const f16x8 (&bfr)[4][8],
                                             int row, int ln7, int lq,
                                             float (&Sa)[4], float (&Wa)[4]) {
    f32x4 acc[4];
#pragma unroll
    for (int p = 0; p < 4; ++p) acc[p] = (f32x4){0.f, 0.f, 0.f, 0.f};
#pragma unroll
    for (int ks = 0; ks < 8; ++ks) {
        const int ch = (ks * 4 + lq) ^ ln7;          // bank-correct swizzle
        const f16x8 a = *(const f16x8*)(pb + row * 256 + ch * 8);
#pragma unroll
        for (int p = 0; p < 4; ++p)
            acc[p] = __builtin_amdgcn_mfma_f32_16x16x32_f16(a, bfr[p][ks], acc[p], 0, 0, 0);
    }
    const f32x4 mkv = *(const f32x4*)(msp + lq * 4);
#pragma unroll
    for (int p = 0; p < 4; ++p) {
        float ssum = 0.f, wsum = 0.f;
#pragma unroll
        for (int r = 0; r < 4; ++r) {
            const float d = 20.f * acc[p][r];
            const float e = mkv[r] * __expf(d - 20.f);
            ssum += e; wsum += e * d;
        }
        Sa[p] += ssum; Wa[p] += wsum;
    }
}

// K3: 256 blocks x 512 thr (8 waves), 1 block/CU. Block: 64 px, all 1280 m.
// Prologue: gload_lds qry -> qtf, normalize -> qs f16 (XOR ^(px&7)), hoist 32
// B-frags/wave to regs. Main: 10 tiles of 128 m, LDS dbuf staged per-wave by
// global_load_lds with counted vmcnt(8); NO inter-wave barriers in the loop.
__global__ __launch_bounds__(512, 2) void main_kernel(const float* __restrict__ qry,
                                                      const _Float16* __restrict__ pro_h,
                                                      const float* __restrict__ maskf,
                                                      float* __restrict__ out) {
    __shared__ __align__(16) _Float16 arena[65536];   // 128 KB: bufs / qtf / qs / red
    __shared__ float ms[1280];
    __shared__ float scr[1024];
    __shared__ float2 stats[64];

    float*     qtf  = (float*)arena;        // 64 KB [c][64px] (prologue)
    _Float16*  qs   = arena + 32768;        // 32 KB (prologue)
    _Float16*  buf0 = arena;                // 64 KB (main)
    _Float16*  buf1 = arena + 32768;        // 64 KB (main)
    float*     red  = (float*)arena;        // 16 KB (epilogue, overlays buf0)

    const int t = threadIdx.x;
    const int w = t >> 6, l = t & 63;
    const int ln = l & 15, lq = l >> 4;
    const int ln7 = ln & 7;
    const int px0 = blockIdx.x * 64;

    // ---- prologue: stage qry tile + masks ----
#pragma unroll
    for (int i = 0; i < 8; ++i) {
        const int c = i * 32 + (t >> 4);
        gload_lds16f(qry + (size_t)c * 16384 + px0 + (t & 15) * 4,
                     qtf + i * 2048 + t * 4);
    }
#pragma unroll
    for (int it = 0; it < 3; ++it) {
        const int idx = it * 512 + t;
        if (idx < 1280) ms[idx] = maskf[idx];
    }
    __syncthreads();   // full drain: qtf + ms ready
    {   // per-px partials
        const int p = t & 63, q = t >> 6;
        float s1 = 0.f, s2 = 0.f;
        for (int cc = 0; cc < 32; ++cc) {
            const float x = qtf[(q * 32 + cc) * 64 + p];
            s1 += x; s2 += x * x;
        }
        scr[q * 64 + p] = s1; scr[512 + q * 64 + p] = s2;
    }
    __syncthreads();
    if (t < 64) {
        float S1 = 0.f, S2 = 0.f;
        for (int q = 0; q < 8; ++q) { S1 += scr[q * 64 + t]; S2 += scr[512 + q * 64 + t]; }
        const float mu = S1 * (1.f / 256.f);
        const float nrm = sqrtf(fmaxf(S2 - 256.f * mu * mu, 0.f));
        stats[t] = make_float2(mu, 1.f / fmaxf(nrm, 1e-4f));
    }
    __syncthreads();
    {   // normalize -> qs f16, chunk g at g ^ (px&7)
        const int px = t & 63, e = t >> 6;
        const float2 st = stats[px];
#pragma unroll
        for (int u = 0; u < 4; ++u) {
            const int g = e * 4 + u;
            f16x8 hv;
#pragma unroll
            for (int j = 0; j < 8; ++j)
                hv[j] = (_Float16)((qtf[(g * 8 + j) * 64 + px] - st.x) * st.y);
            *(f16x8*)(qs + px * 256 + ((g ^ (px & 7)) << 3)) = hv;
        }
    }
    __syncthreads();   // qs ready; qtf dead -> buf0 region free

    // tile 0 staging issued EARLY: its L2 latency hides under the bfr hoist
    stage_tile(pro_h, 0, buf0, w, l);

    // ---- hoist B fragments to registers (ds_read from qs) ----
    f16x8 bfr[4][8];
#pragma unroll
    for (int p = 0; p < 4; ++p) {
        const int px = p * 16 + ln;
        const int sB = px & 7;
#pragma unroll
        for (int ks = 0; ks < 8; ++ks) {
            const int g = ks * 4 + lq;
            bfr[p][ks] = *(const f16x8*)(qs + px * 256 + ((g ^ sB) << 3));
        }
    }
    __syncthreads();   // ALL waves done reading qs -> buf1 region free

    stage_tile(pro_h, 1, buf1, w, l);

    const int row = w * 16 + ln;
    float Sa[4] = {0.f, 0.f, 0.f, 0.f}, Wa[4] = {0.f, 0.f, 0.f, 0.f};

#pragma unroll 1
    for (int tile = 0; tile < 10; ++tile) {
        if (tile < 8) asm volatile("s_waitcnt vmcnt(8)" ::: "memory");
        else          asm volatile("s_waitcnt vmcnt(0)" ::: "memory");
        compute_tile((tile & 1) ? buf1 : buf0, ms + tile * 128 + w * 16,
                     bfr, row, ln7, lq, Sa, Wa);
        if (tile < 8) {
            // all ds_reads of this buffer retired before we overwrite it
            asm volatile("s_waitcnt lgkmcnt(0)" ::: "memory");
            __builtin_amdgcn_sched_barrier(0);
            stage_tile(pro_h, tile + 2, (tile & 1) ? buf1 : buf0, w, l);
        }
    }

    __syncthreads();   // all waves done with buffers -> red overlay safe
#pragma unroll
    for (int p = 0; p < 4; ++p) {
        const int px = p * 16 + ln;
        const int slot = (w * 4 + lq + px) & 31;
        red[px * 32 + slot] = Sa[p];
        red[2048 + px * 32 + slot] = Wa[p];
    }
    __syncthreads();
    if (t < 64) {
        float S = 0.f, W = 0.f;
        for (int s = 0; s < 32; ++s) {
            const int slot = (s + t) & 31;
            S += red[t * 32 + slot];
            W += red[2048 + t * 32 + slot];
        }
        out[px0 + t] = W / S;
    }
}

extern "C" void kernel_launch(void* const* d_in, const int* in_sizes, int n_in,
                              void* d_out, int out_size, void* d_ws, size_t ws_size,
                              hipStream_t stream) {
    const float* qry   = (const float*)d_in[0];   // 256*16384
    const float* sup_x = (const float*)d_in[1];   // 5*256*16384
    const float* sup_y = (const float*)d_in[2];   // 5*16384
    float* out = (float*)d_out;                   // 16384

    char* ws = (char*)d_ws;
    float*     cand_T = (float*)ws;               ws += 256 * 1280 * 4;    // 1.25 MB
    float*     yv_ws  = (float*)ws;               ws += 1280 * 4;
    float*     maskf  = (float*)ws;               ws += 1280 * 4;
    _Float16*  pro_h  = (_Float16*)ws;            /* 640 KB */

    pool_kernel<<<1285, 256, 0, stream>>>(sup_x, sup_y, cand_T, yv_ws);
    fin_kernel<<<81, 256, 0, stream>>>(cand_T, yv_ws, pro_h, maskf);
    main_kernel<<<256, 512, 0, stream>>>(qry, pro_h, maskf, out);
}

// Round 11
// 39.431 us; speedup vs baseline: 5.7546x; 1.0335x over previous
//
#include <hip/hip_runtime.h>
#include <math.h>

typedef _Float16 f16x8 __attribute__((ext_vector_type(8)));
typedef float f32x4 __attribute__((ext_vector_type(4)));

// ---------------------------------------------------------------------------
// qry (256c,16384px) f32; sup_x (5,256,128,128) f32; sup_y (5,128,128) f32.
// M=1280 protos, C=256. out (16384) f32.
// pred[px] = sum_m softmax(mask? d : NEG)_m * d_m, d = 20*<q_n[px], p_n[m]>.
// Identity: sum_c q_n[c] = 0 (mean-centered) => <q_n, (x-mu)*inv> = inv*<q_n,x>
// => MFMA runs on RAW pooled x (f16); epilogue applies d = alpha[m]*acc,
// alpha = 20/max(||x-mu||,1e-4) from per-block partial sums (deterministic).
// d <= 20 -> fixed-max softmax: e = mk*exp(d-20). Masked -> exactly 0.
// pro_raw PRE-SWIZZLED: row m, 16B chunk g stored at g ^ (m&7) -> linear
// global_load_lds staging + conflict-free ds_read_b128 at ch = (ks*4+lq)^ln7.
// R9 lesson: cooperative grid.sync ~90us -- separate kernels. 2 launches only.
// ---------------------------------------------------------------------------

// K1: blocks 0..639 = (s, gy, cq): pool 32 channels x 16 cells of shot s,
//     grid-row gy; write pro_raw[m][c-chunks] f16 (swizzled) + psum partials.
//     Blocks 640..644: pool sup_y shot r -> yv_ws.
__global__ __launch_bounds__(256) void pool_kernel(const float* __restrict__ sup_x,
                                                   const float* __restrict__ sup_y,
                                                   _Float16* __restrict__ pro_raw,
                                                   float* __restrict__ psum,
                                                   float* __restrict__ yv_ws) {
    const int b = blockIdx.x, t = threadIdx.x;
    if (b < 640) {
        __shared__ float hs[8192];          // 32 KB: [run 256][lane 32] h-4sums
        __shared__ float xa[16][33];        // [gx][c] pooled values, padded
        const int s = b >> 7, rem = b & 127;
        const int gy = rem >> 3, cq = rem & 7;
        const float* base = sup_x + ((size_t)(s * 256 + cq * 32) * 128 + gy * 8) * 128;
        // 256 runs of 512B: run = (c<<3)|r ; wave covers 2 runs per issue
#pragma unroll 8
        for (int i = 0; i < 32; ++i) {
            const int run = i * 8 + (t >> 5);
            const float4 v = *(const float4*)(base + ((size_t)(run >> 3) * 128 + (run & 7)) * 128 + (t & 31) * 4);
            hs[i * 256 + t] = v.x + v.y + v.z + v.w;
        }
        __syncthreads();
#pragma unroll
        for (int e0 = 0; e0 < 2; ++e0) {    // entry e = (c<<4)|gx : sum 8r x 2 halves
            const int e = e0 * 256 + t;
            const int c = e >> 4, gx = e & 15;
            float sum = 0.f;
#pragma unroll
            for (int r = 0; r < 8; ++r)
                sum += hs[(c * 8 + r) * 32 + gx * 2] + hs[(c * 8 + r) * 32 + gx * 2 + 1];
            xa[gx][c] = sum * (1.f / 64.f);
        }
        __syncthreads();
        const int mbase = s * 256 + gy * 16;
        if (t < 64) {                        // write 16m x 4 chunks f16 swizzled
            const int gx = t >> 2, gi = t & 3;
            const int m = mbase + gx;
            const int g = cq * 4 + gi;
            f16x8 hv;
#pragma unroll
            for (int j = 0; j < 8; ++j) hv[j] = (_Float16)xa[gx][gi * 8 + j];
            *(f16x8*)(pro_raw + (size_t)m * 256 + ((g ^ (m & 7)) << 3)) = hv;
        } else if (t < 80) {                 // partial stats over this block's 32 c
            const int gx = t - 64;
            float s1 = 0.f, s2 = 0.f;
#pragma unroll
            for (int c = 0; c < 32; ++c) { const float x = xa[gx][c]; s1 += x; s2 += x * x; }
            const int m = mbase + gx;
            psum[m * 16 + cq * 2]     = s1;
            psum[m * 16 + cq * 2 + 1] = s2;
        }
    } else {
        const int r = b - 640;
        const int gy = t >> 4, gx = t & 15;
        const float* base = sup_y + r * 16384 + gy * 1024 + gx * 8;
        float sum = 0.f;
#pragma unroll
        for (int rr = 0; rr < 8; ++rr) {
            const float4 a = *(const float4*)(base + rr * 128);
            const float4 bb = *(const float4*)(base + rr * 128 + 4);
            sum += a.x + a.y + a.z + a.w + bb.x + bb.y + bb.z + bb.w;
        }
        yv_ws[r * 256 + t] = sum * (1.f / 64.f);
    }
}

__device__ __forceinline__ void gload_lds16h(const _Float16* g, _Float16* l) {
    __builtin_amdgcn_global_load_lds((const __attribute__((address_space(1))) unsigned int*)g,
                                     (__attribute__((address_space(3))) unsigned int*)l,
                                     16, 0, 0);
}
__device__ __forceinline__ void gload_lds16f(const float* g, float* l) {
    __builtin_amdgcn_global_load_lds((const __attribute__((address_space(1))) unsigned int*)g,
                                     (__attribute__((address_space(3))) unsigned int*)l,
                                     16, 0, 0);
}

// stage one 128m x 256c f16 tile: wave w stages ITS OWN 16 rows (8KB slice)
__device__ __forceinline__ void stage_tile(const _Float16* __restrict__ pro_raw,
                                           int tile, _Float16* dst, int w, int l) {
#pragma unroll
    for (int i = 0; i < 8; ++i) {
        const int off = w * 4096 + i * 512 + l * 8;
        gload_lds16h(pro_raw + (size_t)tile * 32768 + off, dst + off);
    }
}

// compute one 128-m tile: wave owns rows w*16..w*16+15.
// epilogue: d = alpha[m]*acc ; e = mk*exp(d-20) ; S += e ; W += e*d
__device__ __forceinline__ void compute_tile(const _Float16* __restrict__ pb,
                                             const float* __restrict__ msp,
                                             const float* __restrict__ asp,
                                             const f16x8 (&bfr)[4][8],
                                             int row, int ln7, int lq,
                                             float (&Sa)[4], float (&Wa)[4]) {
    f32x4 acc[4];
#pragma unroll
    for (int p = 0; p < 4; ++p) acc[p] = (f32x4){0.f, 0.f, 0.f, 0.f};
#pragma unroll
    for (int ks = 0; ks < 8; ++ks) {
        const int ch = (ks * 4 + lq) ^ ln7;          // bank-correct swizzle
        const f16x8 a = *(const f16x8*)(pb + row * 256 + ch * 8);
#pragma unroll
        for (int p = 0; p < 4; ++p)
            acc[p] = __builtin_amdgcn_mfma_f32_16x16x32_f16(a, bfr[p][ks], acc[p], 0, 0, 0);
    }
    const f32x4 mkv = *(const f32x4*)(msp + lq * 4);
    const f32x4 av  = *(const f32x4*)(asp + lq * 4);
#pragma unroll
    for (int p = 0; p < 4; ++p) {
        float ssum = 0.f, wsum = 0.f;
#pragma unroll
        for (int r = 0; r < 4; ++r) {
            const float d = av[r] * acc[p][r];
            const float e = mkv[r] * __expf(d - 20.f);
            ssum += e; wsum += e * d;
        }
        Sa[p] += ssum; Wa[p] += wsum;
    }
}

// K2: 256 blocks x 512 thr. Prologue: stage qry -> qtf (async), meanwhile
// reduce psum -> alpha[m] + masks from yv_ws; qnorm -> qs f16; hoist B-frags.
// Main: 10 tiles of 128 m, per-wave dbuf + counted vmcnt (R10 pipeline).
__global__ __launch_bounds__(512, 2) void main_kernel(const float* __restrict__ qry,
                                                      const _Float16* __restrict__ pro_raw,
                                                      const float* __restrict__ psum,
                                                      const float* __restrict__ yv_ws,
                                                      float* __restrict__ out) {
    __shared__ __align__(16) _Float16 arena[65536];   // 128 KB
    __shared__ float ms[1280];
    __shared__ float alf[1280];
    __shared__ float scr[1024];
    __shared__ float2 stats[64];
    __shared__ int iflags[2];

    float*     qtf  = (float*)arena;        // 64 KB [c][64px] (prologue)
    _Float16*  qs   = arena + 32768;        // bytes [64K,96K) (prologue)
    _Float16*  buf0 = arena;                // bytes [0,64K)   (main)
    _Float16*  buf1 = arena + 32768;        // bytes [64K,128K)(main)
    float*     red  = (float*)arena;        // 16 KB (epilogue, overlays buf0)

    const int t = threadIdx.x;
    const int w = t >> 6, l = t & 63;
    const int ln = l & 15, lq = l >> 4;
    const int ln7 = ln & 7;
    const int px0 = blockIdx.x * 64;

    if (t < 2) iflags[t] = 0;
    __syncthreads();

    // ---- issue qry staging (latency hidden by alpha/mask compute below) ----
#pragma unroll
    for (int i = 0; i < 8; ++i) {
        const int c = i * 32 + (t >> 4);
        gload_lds16f(qry + (size_t)c * 16384 + px0 + (t & 15) * 4,
                     qtf + i * 2048 + t * 4);
    }

    // ---- alpha[m] from psum partials + mask flags (m = t, t+512, t+1024) ----
    float yv3[3];
    int f0 = 0, f1 = 0;
#pragma unroll
    for (int k = 0; k < 3; ++k) {
        const int m = t + k * 512;
        if (m < 1280) {
            const f32x4 p0 = *(const f32x4*)(psum + m * 16);
            const f32x4 p1 = *(const f32x4*)(psum + m * 16 + 4);
            const f32x4 p2 = *(const f32x4*)(psum + m * 16 + 8);
            const f32x4 p3 = *(const f32x4*)(psum + m * 16 + 12);
            const float S1 = p0[0] + p0[2] + p1[0] + p1[2] + p2[0] + p2[2] + p3[0] + p3[2];
            const float S2 = p0[1] + p0[3] + p1[1] + p1[3] + p2[1] + p2[3] + p3[1] + p3[3];
            alf[m] = 20.f / fmaxf(sqrtf(fmaxf(S2 - S1 * S1 * (1.f / 256.f), 0.f)), 1e-4f);
            const float y = yv_ws[m];
            yv3[k] = y;
            if (y > 0.5f) f0 = 1;
            if (y > 0.1f) f1 = 1;
        }
    }
    if (f0) atomicOr(&iflags[0], 1);
    if (f1) atomicOr(&iflags[1], 1);
    __syncthreads();   // full drain: qtf ready, flags final
    {
        const int mode = iflags[0] ? 0 : (iflags[1] ? 1 : 2);
#pragma unroll
        for (int k = 0; k < 3; ++k) {
            const int m = t + k * 512;
            if (m < 1280)
                ms[m] = (mode == 0) ? (yv3[k] > 0.5f ? 1.f : 0.f)
                      : (mode == 1) ? (yv3[k] > 0.1f ? 1.f : 0.f) : 1.f;
        }
    }

    // ---- qnorm: per-px stats then f16 convert into qs (swizzled) ----
    {
        const int p = t & 63, q = t >> 6;
        float s1 = 0.f, s2 = 0.f;
        for (int cc = 0; cc < 32; ++cc) {
            const float x = qtf[(q * 32 + cc) * 64 + p];
            s1 += x; s2 += x * x;
        }
        scr[q * 64 + p] = s1; scr[512 + q * 64 + p] = s2;
    }
    __syncthreads();
    if (t < 64) {
        float S1 = 0.f, S2 = 0.f;
        for (int q = 0; q < 8; ++q) { S1 += scr[q * 64 + t]; S2 += scr[512 + q * 64 + t]; }
        const float mu = S1 * (1.f / 256.f);
        const float nrm = sqrtf(fmaxf(S2 - 256.f * mu * mu, 0.f));
        stats[t] = make_float2(mu, 1.f / fmaxf(nrm, 1e-4f));
    }
    __syncthreads();
    {
        const int px = t & 63, e = t >> 6;
        const float2 st = stats[px];
#pragma unroll
        for (int u = 0; u < 4; ++u) {
            const int g = e * 4 + u;
            f16x8 hv;
#pragma unroll
            for (int j = 0; j < 8; ++j)
                hv[j] = (_Float16)((qtf[(g * 8 + j) * 64 + px] - st.x) * st.y);
            *(f16x8*)(qs + px * 256 + ((g ^ (px & 7)) << 3)) = hv;
        }
    }
    __syncthreads();   // qs ready; qtf dead -> buf0 region free

    stage_tile(pro_raw, 0, buf0, w, l);   // overlaps bfr hoist

    f16x8 bfr[4][8];
#pragma unroll
    for (int p = 0; p < 4; ++p) {
        const int px = p * 16 + ln;
        const int sB = px & 7;
#pragma unroll
        for (int ks = 0; ks < 8; ++ks) {
            const int g = ks * 4 + lq;
            bfr[p][ks] = *(const f16x8*)(qs + px * 256 + ((g ^ sB) << 3));
        }
    }
    __syncthreads();   // all waves done reading qs -> buf1 region free

    stage_tile(pro_raw, 1, buf1, w, l);

    const int row = w * 16 + ln;
    float Sa[4] = {0.f, 0.f, 0.f, 0.f}, Wa[4] = {0.f, 0.f, 0.f, 0.f};

#pragma unroll 1
    for (int tile = 0; tile < 10; ++tile) {
        if (tile < 8) asm volatile("s_waitcnt vmcnt(8)" ::: "memory");
        else          asm volatile("s_waitcnt vmcnt(0)" ::: "memory");
        compute_tile((tile & 1) ? buf1 : buf0,
                     ms + tile * 128 + w * 16, alf + tile * 128 + w * 16,
                     bfr, row, ln7, lq, Sa, Wa);
        if (tile < 8) {
            asm volatile("s_waitcnt lgkmcnt(0)" ::: "memory");
            __builtin_amdgcn_sched_barrier(0);
            stage_tile(pro_raw, tile + 2, (tile & 1) ? buf1 : buf0, w, l);
        }
    }

    __syncthreads();   // all waves done with buffers -> red overlay safe
#pragma unroll
    for (int p = 0; p < 4; ++p) {
        const int px = p * 16 + ln;
        const int slot = (w * 4 + lq + px) & 31;
        red[px * 32 + slot] = Sa[p];
        red[2048 + px * 32 + slot] = Wa[p];
    }
    __syncthreads();
    if (t < 64) {
        float S = 0.f, W = 0.f;
        for (int s = 0; s < 32; ++s) {
            const int slot = (s + t) & 31;
            S += red[t * 32 + slot];
            W += red[2048 + t * 32 + slot];
        }
        out[px0 + t] = W / S;
    }
}

extern "C" void kernel_launch(void* const* d_in, const int* in_sizes, int n_in,
                              void* d_out, int out_size, void* d_ws, size_t ws_size,
                              hipStream_t stream) {
    const float* qry   = (const float*)d_in[0];   // 256*16384
    const float* sup_x = (const float*)d_in[1];   // 5*256*16384
    const float* sup_y = (const float*)d_in[2];   // 5*16384
    float* out = (float*)d_out;                   // 16384

    char* ws = (char*)d_ws;
    _Float16*  pro_raw = (_Float16*)ws;           ws += 1280 * 256 * 2;   // 640 KB
    float*     psum    = (float*)ws;              ws += 1280 * 16 * 4;    // 80 KB
    float*     yv_ws   = (float*)ws;              /* 5 KB */

    pool_kernel<<<645, 256, 0, stream>>>(sup_x, sup_y, pro_raw, psum, yv_ws);
    main_kernel<<<256, 512, 0, stream>>>(qry, pro_raw, psum, yv_ws, out);
}